// Round 13
// baseline (46.566 us; speedup 1.0000x reference)
//
#include <hip/hip_runtime.h>

// CHMM forward-backward, clone-structured deterministic emission (n_clones=8).
// Single regular-launch kernel, 256 scan blocks + 1024 fill blocks x 256 thr.
// Output dwords PARTITIONED by ownership derived from obs (no fill<->scan
// ordering; every byte exactly one writer -> replay-safe by construction).
// Fill blocks: 8 rows each, nontemporal float4 streaming zeros (L2 bypass),
// 8 special roles/row for window-adjacent + straddler dwords (incl. the
// col 8*ob-1 dword missed in R12). Scan blocks: chunked 8-dim scan hierarchy
// over relaxed agent-scope flags; log-lik via chunk formula (log(sum(a@P))
// + ke*ln2) instead of 32 serial logf in the rescan.

#define NSTATES 4096
#define NBLK    8
#define LSEQ    8192
#define NSTEPS  8191
#define CHK     32
#define NCH     256
#define NGRP    16
#define GSZ     16
#define NFILL   1024
#define FROWS   8

// ws float offsets
#define OFF_P   0u       // [NCH*64]  chunk products, col-major [c*64 + col*8 + row]
#define OFF_G2  16384u   // [NGRP*64] group products, col-major
#define OFF_LLP 17408u   // [NCH]     per-chunk log-lik partials
// ws uint offsets (flags)
#define FLG_F1  17664u   // [NCH]
#define FLG_F2  17920u   // [NGRP]
#define FLG_F3  17936u   // [NCH]
#define MAGIC   0x5A17C0DEu

__device__ __forceinline__ float aload(float* p) {
    return __hip_atomic_load(p, __ATOMIC_RELAXED, __HIP_MEMORY_SCOPE_AGENT);
}
__device__ __forceinline__ void astore(float* p, float v) {
    __hip_atomic_store(p, v, __ATOMIC_RELAXED, __HIP_MEMORY_SCOPE_AGENT);
}
__device__ __forceinline__ unsigned aloadu(unsigned* p) {
    return __hip_atomic_load(p, __ATOMIC_RELAXED, __HIP_MEMORY_SCOPE_AGENT);
}
__device__ __forceinline__ void astoreu(unsigned* p, unsigned v) {
    __hip_atomic_store(p, v, __ATOMIC_RELAXED, __HIP_MEMORY_SCOPE_AGENT);
}
#define VMFENCE()  asm volatile("s_waitcnt vmcnt(0)" ::: "memory")
#define LDSFENCE() asm volatile("s_waitcnt lgkmcnt(0)" ::: "memory")

typedef float floatx4 __attribute__((ext_vector_type(4)));
__device__ __forceinline__ void ntz4(float4* p) {
    floatx4 z = {0.f, 0.f, 0.f, 0.f};
    __builtin_nontemporal_store(z, reinterpret_cast<floatx4*>(p));
}

__device__ __forceinline__ int expof(float x) {
    return (int)((__float_as_uint(x) >> 23) & 0xff) - 127;
}

__global__ __launch_bounds__(256) void kFB(const float* __restrict__ T,
                                           const float* __restrict__ Pi,
                                           const int* __restrict__ obs,
                                           float* __restrict__ out,
                                           float* __restrict__ ws)
{
    __shared__ float sM[CHK * 64];
    __shared__ float sDuty[GSZ * 64];
    __shared__ float sG2[NGRP * 64];
    __shared__ float sGP[GSZ * 64];
    __shared__ float sA[(CHK + 1) * 8];
    __shared__ float sB[(CHK + 1) * 8];
    __shared__ float sGv[CHK * 8];
    __shared__ int   sObs[CHK + 1];
    unsigned* flg = reinterpret_cast<unsigned*>(ws);
    const int tid = threadIdx.x;
    const int blk = blockIdx.x;

    if (blk >= NCH) {
        // ============= FILL block: 8 rows, nt streaming zeros ==============
        const int f = blk - NCH;
        const int r0 = f * FROWS;
        if (tid < FROWS + 1) {
            int t = r0 - 1 + tid;
            sObs[tid] = (t >= 0) ? obs[t] : 0;   // sObs[0]=obs[r0-1]
        }
        __syncthreads();
        float4* o4 = reinterpret_cast<float4*>(out);
#pragma unroll 4
        for (int q = tid; q < FROWS * 1024; q += 256) {
            int rr = q >> 10, pos = q & 1023;
            int w2 = sObs[1 + rr] * 2;
            if (pos != 0 && (unsigned)(pos - w2) > 2u)
                ntz4(&o4[(r0 + rr) * 1024 + pos]);
        }
        if (tid < FROWS * 8) {
            const int rr = tid >> 3, role = tid & 7;
            const int r = r0 + rr;
            const int ob = sObs[1 + rr];
            const int obPrev = sObs[rr];
            const size_t rowBase = (size_t)r * 4096;  // out dword: straddler start
            if (role == 0) {        // prev row col 4095
                if (r != 0 && obPrev != 511) out[rowBase] = 0.f;
            } else if (role <= 3) { // cols 0..2
                if (ob != 0) out[rowBase + role] = 0.f;
            } else if (role <= 6) { // cols 8ob+8..8ob+10
                if (ob <= 510) out[rowBase + 8 * ob + 9 + (role - 4)] = 0.f;
            } else {                // col 8ob-1 (R12's missing dword)
                if (ob >= 1) out[rowBase + 8 * ob] = 0.f;
            }
        }
        if (f == NFILL - 1 && tid == 255 && sObs[FROWS] != 511)
            out[(size_t)LSEQ * NSTATES] = 0.f;       // row 8191 col 4095
        return;
    }

    // ==================== SCAN block (wave 0 only) =========================
    if (tid >= 64) return;
    const int b = blk;
    const int g = b >> 4, rIn = b & 15;
    const int t0 = b * CHK;
    const int n = min(CHK, NSTEPS - t0);  // 32; block 255: 31
    float ll0 = 0.f;
    int kTot = 0;
    const int i = tid >> 3, j = tid & 7;

    // ---- gather own chunk's 8x8 T-blocks into LDS -------------------------
    for (int u = tid; u < n * 8; u += 64) {
        int dt = u >> 3, ri = u & 7;
        int t = t0 + dt;
        int row = obs[t] * NBLK + ri;
        int col = obs[t + 1] * NBLK;
        const float4* src = reinterpret_cast<const float4*>(T + (size_t)row * NSTATES + col);
        float4 v0 = src[0], v1 = src[1];
        float vv[8] = {v0.x, v0.y, v0.z, v0.w, v1.x, v1.y, v1.z, v1.w};
        float* base = &sM[dt * 64 + ri];               // [dt*64 + col*8 + row]
#pragma unroll
        for (int jj = 0; jj < 8; ++jj) base[jj * 8] = vv[jj];
    }
    if (tid < CHK) sObs[tid] = obs[t0 + tid];
    LDSFENCE();

    // ---- chunk product (exponent-tracked): lane (i,j) holds P[i][j] ----
    {
        float p = sM[j * 8 + i];
        float m[8], mn[8];
#pragma unroll
        for (int k = 0; k < 8; ++k) m[k] = sM[64 + j * 8 + k];
        for (int dt = 1; dt < n; ++dt) {
            int dtn = min(dt + 1, n - 1);
#pragma unroll
            for (int k = 0; k < 8; ++k) mn[k] = sM[dtn * 64 + j * 8 + k];
            float pn = 0.f;
#pragma unroll
            for (int k = 0; k < 8; ++k) pn = fmaf(__shfl(p, i * 8 + k, 64), m[k], pn);
            if ((dt & 3) == 0) {
                int ke = expof(__shfl(pn, 0, 64));
                pn = ldexpf(pn, -ke);
                kTot += ke;
            }
            p = pn;
#pragma unroll
            for (int k = 0; k < 8; ++k) m[k] = mn[k];
        }
        {
            int ke = expof(__shfl(p, 0, 64));
            p = ldexpf(p, -ke);
            kTot += ke;
        }
        astore(&ws[OFF_P + b * 64 + j * 8 + i], p);
    }
    VMFENCE();
    if (tid == 0) astoreu(&flg[FLG_F1 + b], MAGIC);

    // ---- group duty (blocks 0..15): product of group's 16 P's ----
    if (b < NGRP) {
        for (;;) {
            bool ok = true;
            if (tid < GSZ)
                ok = aloadu(&flg[FLG_F1 + GSZ * b + tid]) == MAGIC;
            if (__all(ok)) break;
            __builtin_amdgcn_s_sleep(1);
        }
        {   // pipelined register staging: 16 loads in flight
            float rb[16];
#pragma unroll
            for (int k = 0; k < 16; ++k)
                rb[k] = aload(&ws[OFF_P + (size_t)b * GSZ * 64 + k * 64 + tid]);
#pragma unroll
            for (int k = 0; k < 16; ++k) sDuty[k * 64 + tid] = rb[k];
        }
        LDSFENCE();
        float p = sDuty[j * 8 + i];
        float m[8], mn[8];
#pragma unroll
        for (int k = 0; k < 8; ++k) m[k] = sDuty[64 + j * 8 + k];
        for (int r = 1; r < GSZ; ++r) {
            int rn = min(r + 1, GSZ - 1);
#pragma unroll
            for (int k = 0; k < 8; ++k) mn[k] = sDuty[rn * 64 + j * 8 + k];
            float pn = 0.f;
#pragma unroll
            for (int k = 0; k < 8; ++k) pn = fmaf(__shfl(p, i * 8 + k, 64), m[k], pn);
            if ((r & 1) == 0 || r == GSZ - 1) {
                int ke = expof(__shfl(pn, 0, 64));
                pn = ldexpf(pn, -ke);
            }
            p = pn;
#pragma unroll
            for (int k = 0; k < 8; ++k) m[k] = mn[k];
        }
        astore(&ws[OFF_G2 + b * 64 + j * 8 + i], p);
        VMFENCE();
        if (tid == 0) astoreu(&flg[FLG_F2 + b], MAGIC);
    }

    // ---- wait for all 16 F2 (transitively covers all F1 payloads) ----
    for (;;) {
        bool ok = true;
        if (tid < NGRP)
            ok = aloadu(&flg[FLG_F2 + tid]) == MAGIC;
        if (__all(ok)) break;
        __builtin_amdgcn_s_sleep(1);
    }
    {   // pipelined staging of sG2 + own group's P (32 loads in flight)
        float ra[16], rb[16];
#pragma unroll
        for (int k = 0; k < 16; ++k) ra[k] = aload(&ws[OFF_G2 + k * 64 + tid]);
#pragma unroll
        for (int k = 0; k < 16; ++k)
            rb[k] = aload(&ws[OFF_P + (size_t)g * GSZ * 64 + k * 64 + tid]);
#pragma unroll
        for (int k = 0; k < 16; ++k) sG2[k * 64 + tid] = ra[k];
#pragma unroll
        for (int k = 0; k < 16; ++k) sGP[k * 64 + tid] = rb[k];
    }
    LDSFENCE();

    if (tid < 16) {
        const int grp = tid >> 3, l8 = tid & 7;
        const int st = grp ? 8 : 1;
        const int boff = grp ? l8 : l8 * 8;
        // ---- redundant global dual scan over 16 group products ----
        float v[8], vb[8];
        {
            float a = Pi[obs[0] * NBLK + l8];
            float s0 = a;
            s0 += __shfl_xor(s0, 1); s0 += __shfl_xor(s0, 2); s0 += __shfl_xor(s0, 4);
            float rs0 = 1.0f / s0;
#pragma unroll
            for (int q = 0; q < 8; ++q) v[q] = grp ? 0.125f : __shfl(a, q, 8) * rs0;
            ll0 = __logf(s0);
        }
        const int cap = grp ? (NGRP - 1 - g) : g;
        if (cap == 0) {
#pragma unroll
            for (int q = 0; q < 8; ++q) vb[q] = v[q];
        }
        for (int r = 0; r < NGRP - 1; ++r) {
            int gi = grp ? (NGRP - 1 - r) : r;
            const float* mb = &sG2[gi * 64 + boff];
            float m[8];
#pragma unroll
            for (int q = 0; q < 8; ++q) m[q] = mb[q * st];
            float u = 0.f;
#pragma unroll
            for (int q = 0; q < 8; ++q) u = fmaf(v[q], m[q], u);
            float s = 0.f;
#pragma unroll
            for (int q = 0; q < 8; ++q) { float x = __shfl(u, q, 8); v[q] = x; s += x; }
            float rs = 1.0f / s;
#pragma unroll
            for (int q = 0; q < 8; ++q) v[q] *= rs;
            if (r + 1 == cap) {
#pragma unroll
                for (int q = 0; q < 8; ++q) vb[q] = v[q];
            }
        }
        // ---- predicated advance to own chunk boundary (<=15 steps) ----
#pragma unroll
        for (int q = 0; q < 8; ++q) v[q] = vb[q];
        const int cnt = grp ? (GSZ - 1 - rIn) : rIn;
        for (int q = 0; q < GSZ - 1; ++q) {
            bool act = q < cnt;
            int qc = act ? q : 0;
            int lc = grp ? (GSZ - 1 - qc) : qc;
            const float* mb = &sGP[lc * 64 + boff];
            float m[8];
#pragma unroll
            for (int k = 0; k < 8; ++k) m[k] = mb[k * st];
            float u = 0.f;
#pragma unroll
            for (int k = 0; k < 8; ++k) u = fmaf(v[k], m[k], u);
            float s = 0.f;
            float vn[8];
#pragma unroll
            for (int k = 0; k < 8; ++k) { float x = __shfl(u, k, 8); vn[k] = x; s += x; }
            float rs = 1.0f / s;
#pragma unroll
            for (int k = 0; k < 8; ++k) v[k] = act ? vn[k] * rs : v[k];
        }
        // ---- per-chunk log-lik from chunk product (replaces 32 logf) ----
        if (grp == 0) {
            float u = 0.f;
#pragma unroll
            for (int q2 = 0; q2 < 8; ++q2)
                u = fmaf(v[q2], sGP[rIn * 64 + l8 * 8 + q2], u);
            float ssum = u;
            ssum += __shfl_xor(ssum, 1); ssum += __shfl_xor(ssum, 2); ssum += __shfl_xor(ssum, 4);
            if (l8 == 0)
                astore(&ws[OFF_LLP + b], __logf(ssum) + (float)kTot * 0.69314718055994531f);
        }
        // ---- within-chunk dual rescan from sM (no logf) ----
        float* hist = grp ? sB : sA;
        hist[(grp ? n : 0) * 8 + l8] = v[l8];
        int mt0 = grp ? (n - 1) : 0;
        float m[8], mn[8];
#pragma unroll
        for (int q = 0; q < 8; ++q) m[q] = sM[mt0 * 64 + boff + q * st];
        for (int rr = 0; rr < n; ++rr) {
            int rn2 = min(rr + 1, n - 1);
            int mtn = grp ? (n - 1 - rn2) : rn2;
#pragma unroll
            for (int q = 0; q < 8; ++q) mn[q] = sM[mtn * 64 + boff + q * st];
            float u = 0.f;
#pragma unroll
            for (int q = 0; q < 8; ++q) u = fmaf(v[q], m[q], u);
            float s = 0.f;
#pragma unroll
            for (int q = 0; q < 8; ++q) { float x = __shfl(u, q, 8); v[q] = x; s += x; }
            float rs = 1.0f / s;
#pragma unroll
            for (int q = 0; q < 8; ++q) v[q] *= rs;
            hist[(grp ? (n - 1 - rr) : (rr + 1)) * 8 + l8] = v[l8];
#pragma unroll
            for (int q = 0; q < 8; ++q) m[q] = mn[q];
        }
    }
    LDSFENCE();   // sA/sB visible across wave 0

    // ---- normalized gamma -> sGv ------------------------------------------
    {
        const int r0l = tid >> 3, ii = tid & 7;
#pragma unroll
        for (int k = 0; k < 4; ++k) {
            int rr = r0l + k * 8;
            float gp = sA[rr * 8 + ii] * sB[rr * 8 + ii];
            float gs = gp;
            gs += __shfl_xor(gs, 1); gs += __shfl_xor(gs, 2); gs += __shfl_xor(gs, 4);
            sGv[rr * 8 + ii] = gp / gs;
        }
    }
    LDSFENCE();
    VMFENCE();
    if (tid == 0) astoreu(&flg[FLG_F3 + b], MAGIC);

    // ---- scatter: lane rr<32 writes row t0+rr's window dwords -------------
    if (tid < CHK) {
        const int r = t0 + tid;
        const int ob = sObs[tid];
        const size_t W = (size_t)r * NSTATES + ob * NBLK;   // gamma flat index
        const float* gv = &sGv[tid * 8];
        out[W + 1] = gv[0];
        out[W + 2] = gv[1];
        out[W + 3] = gv[2];
        reinterpret_cast<float4*>(out)[W / 4 + 1] = make_float4(gv[3], gv[4], gv[5], gv[6]);
        out[W + 8] = gv[7];
    }

    // ---- block 0: deterministic log-lik reduction -> out[0] ---------------
    if (b == 0) {
        for (;;) {
            bool ok = true;
#pragma unroll
            for (int q = 0; q < 4; ++q)
                ok = ok && (aloadu(&flg[FLG_F3 + tid * 4 + q]) == MAGIC);
            if (__all(ok)) break;
            __builtin_amdgcn_s_sleep(1);
        }
        float part = 0.f;
#pragma unroll
        for (int q = 0; q < 4; ++q) part += aload(&ws[OFF_LLP + tid * 4 + q]);
        part += __shfl_xor(part, 32); part += __shfl_xor(part, 16);
        part += __shfl_xor(part, 8);  part += __shfl_xor(part, 4);
        part += __shfl_xor(part, 2);  part += __shfl_xor(part, 1);
        if (tid == 0) out[0] = part + ll0;
    }
}

extern "C" void kernel_launch(void* const* d_in, const int* in_sizes, int n_in,
                              void* d_out, int out_size, void* d_ws, size_t ws_size,
                              hipStream_t stream)
{
    const float* T   = (const float*)d_in[0];
    const float* Pi  = (const float*)d_in[1];
    const int*   obs = (const int*)d_in[2];
    float* out = (float*)d_out;
    float* ws  = (float*)d_ws;

    kFB<<<NCH + NFILL, 256, 0, stream>>>(T, Pi, obs, out, ws);
}

// Round 14
// 42.093 us; speedup vs baseline: 1.1062x; 1.1062x over previous
//
#include <hip/hip_runtime.h>

// CHMM forward-backward, clone-structured deterministic emission (n_clones=8).
// Single regular-launch kernel, 256 scan + 256 fill blocks x 256 threads.
// Output dwords PARTITIONED by ownership derived from obs (no fill<->scan
// ordering; every byte exactly one writer -> replay-safe by construction).
// R14 = R12 fill structure (plain cached float4 stores, 32 rows/block --
// R13's nt-stores + 8-row granularity REGRESSED 41.9->46.6) + R13's two safe
// deltas: the missing-dword fix (col 8*ob-1, role 7) and chunk-formula
// log-lik (log(sum(a@P)) + ke*ln2, no serial logf in the rescan).

#define NSTATES 4096
#define NBLK    8
#define LSEQ    8192
#define NSTEPS  8191
#define CHK     32
#define NCH     256
#define NGRP    16
#define GSZ     16

// ws float offsets
#define OFF_P   0u       // [NCH*64]  chunk products, col-major [c*64 + col*8 + row]
#define OFF_G2  16384u   // [NGRP*64] group products, col-major
#define OFF_LLP 17408u   // [NCH]     per-chunk log-lik partials
// ws uint offsets (flags)
#define FLG_F1  17664u   // [NCH]
#define FLG_F2  17920u   // [NGRP]
#define FLG_F3  17936u   // [NCH]
#define MAGIC   0x5A17C0DEu

__device__ __forceinline__ float aload(float* p) {
    return __hip_atomic_load(p, __ATOMIC_RELAXED, __HIP_MEMORY_SCOPE_AGENT);
}
__device__ __forceinline__ void astore(float* p, float v) {
    __hip_atomic_store(p, v, __ATOMIC_RELAXED, __HIP_MEMORY_SCOPE_AGENT);
}
__device__ __forceinline__ unsigned aloadu(unsigned* p) {
    return __hip_atomic_load(p, __ATOMIC_RELAXED, __HIP_MEMORY_SCOPE_AGENT);
}
__device__ __forceinline__ void astoreu(unsigned* p, unsigned v) {
    __hip_atomic_store(p, v, __ATOMIC_RELAXED, __HIP_MEMORY_SCOPE_AGENT);
}
#define VMFENCE()  asm volatile("s_waitcnt vmcnt(0)" ::: "memory")
#define LDSFENCE() asm volatile("s_waitcnt lgkmcnt(0)" ::: "memory")

__device__ __forceinline__ int expof(float x) {
    return (int)((__float_as_uint(x) >> 23) & 0xff) - 127;
}

__global__ __launch_bounds__(256) void kFB(const float* __restrict__ T,
                                           const float* __restrict__ Pi,
                                           const int* __restrict__ obs,
                                           float* __restrict__ out,
                                           float* __restrict__ ws)
{
    __shared__ float sM[CHK * 64];
    __shared__ float sDuty[GSZ * 64];
    __shared__ float sG2[NGRP * 64];
    __shared__ float sGP[GSZ * 64];
    __shared__ float sA[(CHK + 1) * 8];
    __shared__ float sB[(CHK + 1) * 8];
    __shared__ float sGv[CHK * 8];
    __shared__ int   sObs[CHK + 1];
    unsigned* flg = reinterpret_cast<unsigned*>(ws);
    const int tid = threadIdx.x;
    const int blk = blockIdx.x;

    if (blk >= NCH) {
        // ============= FILL block: pure streaming zeros (no flags) =========
        const int c = blk - NCH;
        const int r0 = c * CHK;
        if (tid < CHK + 1) {
            int t = r0 - 1 + tid;
            sObs[tid] = (t >= 0) ? obs[t] : 0;   // sObs[0]=obs[r0-1]
        }
        __syncthreads();
        float4* o4 = reinterpret_cast<float4*>(out);
        const float4 z = make_float4(0.f, 0.f, 0.f, 0.f);
        // main: per row rr, float4s pos in [1,1024), skip window pos in {w2,w2+1,w2+2}
#pragma unroll 2
        for (int q = tid; q < CHK * 1024; q += 256) {
            int rr = q >> 10, pos = q & 1023;
            int r = r0 + rr;
            int k = r * 1024 + pos;
            int w2 = sObs[1 + rr] * 2;
            if (pos != 0 && (unsigned)(pos - w2) > 2u) o4[k] = z;
        }
        // specials: per row rr = tid>>3, role = tid&7
        {
            const int rr = tid >> 3, role = tid & 7;
            const int r = r0 + rr;
            const int ob = sObs[1 + rr];
            const int obPrev = sObs[rr];              // valid when r>0
            const int m = r * 1024 + ob * 2;          // first skipped float4
            const int ks = r * 1024;                  // straddler float4
            const bool fullStraddle = (r != 0) && (obPrev != 511) && (ob != 0);
            if (role == 0) {
                if (fullStraddle) o4[ks] = z;
                else if (r != 0 && obPrev != 511) out[(size_t)4 * ks] = 0.f;   // prev row col 4095
            } else if (role <= 3) {
                if (!fullStraddle && ob != 0) out[(size_t)4 * ks + role] = 0.f; // cols 0..2
            } else if (role <= 6) {
                if (ob <= 510) out[(size_t)4 * m + 9 + (role - 4)] = 0.f;       // cols w+8..w+10
            } else {
                if (ob >= 1) out[(size_t)4 * m] = 0.f;                          // col 8ob-1 (fix)
            }
            if (tid == 255 && c == NCH - 1 && sObs[CHK] != 511)
                out[(size_t)LSEQ * NSTATES] = 0.f;    // row 8191 col 4095
        }
        return;
    }

    // ==================== SCAN block (wave 0 only) =========================
    if (tid >= 64) return;
    const int b = blk;
    const int g = b >> 4, rIn = b & 15;
    const int t0 = b * CHK;
    const int n = min(CHK, NSTEPS - t0);  // 32; block 255: 31
    float ll0 = 0.f;
    int kTot = 0;
    const int i = tid >> 3, j = tid & 7;

    // ---- gather own chunk's 8x8 T-blocks into LDS -------------------------
    for (int u = tid; u < n * 8; u += 64) {
        int dt = u >> 3, ri = u & 7;
        int t = t0 + dt;
        int row = obs[t] * NBLK + ri;
        int col = obs[t + 1] * NBLK;
        const float4* src = reinterpret_cast<const float4*>(T + (size_t)row * NSTATES + col);
        float4 v0 = src[0], v1 = src[1];
        float vv[8] = {v0.x, v0.y, v0.z, v0.w, v1.x, v1.y, v1.z, v1.w};
        float* base = &sM[dt * 64 + ri];               // [dt*64 + col*8 + row]
#pragma unroll
        for (int jj = 0; jj < 8; ++jj) base[jj * 8] = vv[jj];
    }
    if (tid < CHK) sObs[tid] = obs[t0 + tid];
    LDSFENCE();

    // ---- chunk product (exponent-tracked): lane (i,j) holds P[i][j] ----
    {
        float p = sM[j * 8 + i];
        float m[8], mn[8];
#pragma unroll
        for (int k = 0; k < 8; ++k) m[k] = sM[64 + j * 8 + k];
        for (int dt = 1; dt < n; ++dt) {
            int dtn = min(dt + 1, n - 1);
#pragma unroll
            for (int k = 0; k < 8; ++k) mn[k] = sM[dtn * 64 + j * 8 + k];
            float pn = 0.f;
#pragma unroll
            for (int k = 0; k < 8; ++k) pn = fmaf(__shfl(p, i * 8 + k, 64), m[k], pn);
            if ((dt & 3) == 0) {
                int ke = expof(__shfl(pn, 0, 64));
                pn = ldexpf(pn, -ke);
                kTot += ke;
            }
            p = pn;
#pragma unroll
            for (int k = 0; k < 8; ++k) m[k] = mn[k];
        }
        {
            int ke = expof(__shfl(p, 0, 64));
            p = ldexpf(p, -ke);
            kTot += ke;
        }
        astore(&ws[OFF_P + b * 64 + j * 8 + i], p);
    }
    VMFENCE();
    if (tid == 0) astoreu(&flg[FLG_F1 + b], MAGIC);

    // ---- group duty (blocks 0..15): product of group's 16 P's ----
    if (b < NGRP) {
        for (;;) {
            bool ok = true;
            if (tid < GSZ)
                ok = aloadu(&flg[FLG_F1 + GSZ * b + tid]) == MAGIC;
            if (__all(ok)) break;
            __builtin_amdgcn_s_sleep(1);
        }
        {   // pipelined register staging: 16 loads in flight
            float rb[16];
#pragma unroll
            for (int k = 0; k < 16; ++k)
                rb[k] = aload(&ws[OFF_P + (size_t)b * GSZ * 64 + k * 64 + tid]);
#pragma unroll
            for (int k = 0; k < 16; ++k) sDuty[k * 64 + tid] = rb[k];
        }
        LDSFENCE();
        float p = sDuty[j * 8 + i];
        float m[8], mn[8];
#pragma unroll
        for (int k = 0; k < 8; ++k) m[k] = sDuty[64 + j * 8 + k];
        for (int r = 1; r < GSZ; ++r) {
            int rn = min(r + 1, GSZ - 1);
#pragma unroll
            for (int k = 0; k < 8; ++k) mn[k] = sDuty[rn * 64 + j * 8 + k];
            float pn = 0.f;
#pragma unroll
            for (int k = 0; k < 8; ++k) pn = fmaf(__shfl(p, i * 8 + k, 64), m[k], pn);
            if ((r & 1) == 0 || r == GSZ - 1) {
                int ke = expof(__shfl(pn, 0, 64));
                pn = ldexpf(pn, -ke);
            }
            p = pn;
#pragma unroll
            for (int k = 0; k < 8; ++k) m[k] = mn[k];
        }
        astore(&ws[OFF_G2 + b * 64 + j * 8 + i], p);
        VMFENCE();
        if (tid == 0) astoreu(&flg[FLG_F2 + b], MAGIC);
    }

    // ---- wait for all 16 F2 (transitively covers all F1 payloads) ----
    for (;;) {
        bool ok = true;
        if (tid < NGRP)
            ok = aloadu(&flg[FLG_F2 + tid]) == MAGIC;
        if (__all(ok)) break;
        __builtin_amdgcn_s_sleep(1);
    }
    {   // pipelined staging of sG2 + own group's P (32 loads in flight)
        float ra[16], rb[16];
#pragma unroll
        for (int k = 0; k < 16; ++k) ra[k] = aload(&ws[OFF_G2 + k * 64 + tid]);
#pragma unroll
        for (int k = 0; k < 16; ++k)
            rb[k] = aload(&ws[OFF_P + (size_t)g * GSZ * 64 + k * 64 + tid]);
#pragma unroll
        for (int k = 0; k < 16; ++k) sG2[k * 64 + tid] = ra[k];
#pragma unroll
        for (int k = 0; k < 16; ++k) sGP[k * 64 + tid] = rb[k];
    }
    LDSFENCE();

    if (tid < 16) {
        const int grp = tid >> 3, l8 = tid & 7;
        const int st = grp ? 8 : 1;
        const int boff = grp ? l8 : l8 * 8;
        // ---- redundant global dual scan over 16 group products ----
        float v[8], vb[8];
        {
            float a = Pi[obs[0] * NBLK + l8];
            float s0 = a;
            s0 += __shfl_xor(s0, 1); s0 += __shfl_xor(s0, 2); s0 += __shfl_xor(s0, 4);
            float rs0 = 1.0f / s0;
#pragma unroll
            for (int q = 0; q < 8; ++q) v[q] = grp ? 0.125f : __shfl(a, q, 8) * rs0;
            ll0 = __logf(s0);
        }
        const int cap = grp ? (NGRP - 1 - g) : g;
        if (cap == 0) {
#pragma unroll
            for (int q = 0; q < 8; ++q) vb[q] = v[q];
        }
        for (int r = 0; r < NGRP - 1; ++r) {
            int gi = grp ? (NGRP - 1 - r) : r;
            const float* mb = &sG2[gi * 64 + boff];
            float m[8];
#pragma unroll
            for (int q = 0; q < 8; ++q) m[q] = mb[q * st];
            float u = 0.f;
#pragma unroll
            for (int q = 0; q < 8; ++q) u = fmaf(v[q], m[q], u);
            float s = 0.f;
#pragma unroll
            for (int q = 0; q < 8; ++q) { float x = __shfl(u, q, 8); v[q] = x; s += x; }
            float rs = 1.0f / s;
#pragma unroll
            for (int q = 0; q < 8; ++q) v[q] *= rs;
            if (r + 1 == cap) {
#pragma unroll
                for (int q = 0; q < 8; ++q) vb[q] = v[q];
            }
        }
        // ---- predicated advance to own chunk boundary (<=15 steps) ----
#pragma unroll
        for (int q = 0; q < 8; ++q) v[q] = vb[q];
        const int cnt = grp ? (GSZ - 1 - rIn) : rIn;
        for (int q = 0; q < GSZ - 1; ++q) {
            bool act = q < cnt;
            int qc = act ? q : 0;
            int lc = grp ? (GSZ - 1 - qc) : qc;
            const float* mb = &sGP[lc * 64 + boff];
            float m[8];
#pragma unroll
            for (int k = 0; k < 8; ++k) m[k] = mb[k * st];
            float u = 0.f;
#pragma unroll
            for (int k = 0; k < 8; ++k) u = fmaf(v[k], m[k], u);
            float s = 0.f;
            float vn[8];
#pragma unroll
            for (int k = 0; k < 8; ++k) { float x = __shfl(u, k, 8); vn[k] = x; s += x; }
            float rs = 1.0f / s;
#pragma unroll
            for (int k = 0; k < 8; ++k) v[k] = act ? vn[k] * rs : v[k];
        }
        // ---- per-chunk log-lik from chunk product (replaces 32 logf) ----
        if (grp == 0) {
            float u = 0.f;
#pragma unroll
            for (int q2 = 0; q2 < 8; ++q2)
                u = fmaf(v[q2], sGP[rIn * 64 + l8 * 8 + q2], u);
            float ssum = u;
            ssum += __shfl_xor(ssum, 1); ssum += __shfl_xor(ssum, 2); ssum += __shfl_xor(ssum, 4);
            if (l8 == 0)
                astore(&ws[OFF_LLP + b], __logf(ssum) + (float)kTot * 0.69314718055994531f);
        }
        // ---- within-chunk dual rescan from sM (no logf) ----
        float* hist = grp ? sB : sA;
        hist[(grp ? n : 0) * 8 + l8] = v[l8];
        int mt0 = grp ? (n - 1) : 0;
        float m[8], mn[8];
#pragma unroll
        for (int q = 0; q < 8; ++q) m[q] = sM[mt0 * 64 + boff + q * st];
        for (int rr = 0; rr < n; ++rr) {
            int rn2 = min(rr + 1, n - 1);
            int mtn = grp ? (n - 1 - rn2) : rn2;
#pragma unroll
            for (int q = 0; q < 8; ++q) mn[q] = sM[mtn * 64 + boff + q * st];
            float u = 0.f;
#pragma unroll
            for (int q = 0; q < 8; ++q) u = fmaf(v[q], m[q], u);
            float s = 0.f;
#pragma unroll
            for (int q = 0; q < 8; ++q) { float x = __shfl(u, q, 8); v[q] = x; s += x; }
            float rs = 1.0f / s;
#pragma unroll
            for (int q = 0; q < 8; ++q) v[q] *= rs;
            hist[(grp ? (n - 1 - rr) : (rr + 1)) * 8 + l8] = v[l8];
#pragma unroll
            for (int q = 0; q < 8; ++q) m[q] = mn[q];
        }
    }
    LDSFENCE();   // sA/sB visible across wave 0

    // ---- normalized gamma -> sGv ------------------------------------------
    {
        const int r0l = tid >> 3, ii = tid & 7;
#pragma unroll
        for (int k = 0; k < 4; ++k) {
            int rr = r0l + k * 8;
            float gp = sA[rr * 8 + ii] * sB[rr * 8 + ii];
            float gs = gp;
            gs += __shfl_xor(gs, 1); gs += __shfl_xor(gs, 2); gs += __shfl_xor(gs, 4);
            sGv[rr * 8 + ii] = gp / gs;
        }
    }
    LDSFENCE();
    VMFENCE();
    if (tid == 0) astoreu(&flg[FLG_F3 + b], MAGIC);

    // ---- scatter: lane rr<32 writes row t0+rr's window dwords -------------
    if (tid < CHK) {
        const int r = t0 + tid;
        const int ob = sObs[tid];
        const size_t W = (size_t)r * NSTATES + ob * NBLK;   // gamma flat index
        const float* gv = &sGv[tid * 8];
        out[W + 1] = gv[0];
        out[W + 2] = gv[1];
        out[W + 3] = gv[2];
        reinterpret_cast<float4*>(out)[W / 4 + 1] = make_float4(gv[3], gv[4], gv[5], gv[6]);
        out[W + 8] = gv[7];
    }

    // ---- block 0: deterministic log-lik reduction -> out[0] ---------------
    if (b == 0) {
        for (;;) {
            bool ok = true;
#pragma unroll
            for (int q = 0; q < 4; ++q)
                ok = ok && (aloadu(&flg[FLG_F3 + tid * 4 + q]) == MAGIC);
            if (__all(ok)) break;
            __builtin_amdgcn_s_sleep(1);
        }
        float part = 0.f;
#pragma unroll
        for (int q = 0; q < 4; ++q) part += aload(&ws[OFF_LLP + tid * 4 + q]);
        part += __shfl_xor(part, 32); part += __shfl_xor(part, 16);
        part += __shfl_xor(part, 8);  part += __shfl_xor(part, 4);
        part += __shfl_xor(part, 2);  part += __shfl_xor(part, 1);
        if (tid == 0) out[0] = part + ll0;
    }
}

extern "C" void kernel_launch(void* const* d_in, const int* in_sizes, int n_in,
                              void* d_out, int out_size, void* d_ws, size_t ws_size,
                              hipStream_t stream)
{
    const float* T   = (const float*)d_in[0];
    const float* Pi  = (const float*)d_in[1];
    const int*   obs = (const int*)d_in[2];
    float* out = (float*)d_out;
    float* ws  = (float*)d_ws;

    kFB<<<NCH * 2, 256, 0, stream>>>(T, Pi, obs, out, ws);
}

// Round 15
// 41.182 us; speedup vs baseline: 1.1307x; 1.0221x over previous
//
#include <hip/hip_runtime.h>

// CHMM forward-backward, clone-structured deterministic emission (n_clones=8).
// Single regular-launch kernel, 256 scan + 256 fill blocks x 256 threads.
// Output dwords PARTITIONED by ownership derived from obs (no fill<->scan
// ordering; every byte exactly one writer -> replay-safe by construction).
// R15 = R14 + per-block CHANNEL PHASE ROTATION in the fill sweep: block c
// starts its 512KiB sweep at iteration (c & 127) -> the 256 concurrent fill
// streams spread across all 4KiB channel phases instead of writing the same
// phase in lockstep (512KiB region stride is congruent 0 mod channels x
// interleave). R7's rotation-null was under coop launch (masked; invalid).

#define NSTATES 4096
#define NBLK    8
#define LSEQ    8192
#define NSTEPS  8191
#define CHK     32
#define NCH     256
#define NGRP    16
#define GSZ     16

// ws float offsets
#define OFF_P   0u       // [NCH*64]  chunk products, col-major [c*64 + col*8 + row]
#define OFF_G2  16384u   // [NGRP*64] group products, col-major
#define OFF_LLP 17408u   // [NCH]     per-chunk log-lik partials
// ws uint offsets (flags)
#define FLG_F1  17664u   // [NCH]
#define FLG_F2  17920u   // [NGRP]
#define FLG_F3  17936u   // [NCH]
#define MAGIC   0x5A17C0DEu

__device__ __forceinline__ float aload(float* p) {
    return __hip_atomic_load(p, __ATOMIC_RELAXED, __HIP_MEMORY_SCOPE_AGENT);
}
__device__ __forceinline__ void astore(float* p, float v) {
    __hip_atomic_store(p, v, __ATOMIC_RELAXED, __HIP_MEMORY_SCOPE_AGENT);
}
__device__ __forceinline__ unsigned aloadu(unsigned* p) {
    return __hip_atomic_load(p, __ATOMIC_RELAXED, __HIP_MEMORY_SCOPE_AGENT);
}
__device__ __forceinline__ void astoreu(unsigned* p, unsigned v) {
    __hip_atomic_store(p, v, __ATOMIC_RELAXED, __HIP_MEMORY_SCOPE_AGENT);
}
#define VMFENCE()  asm volatile("s_waitcnt vmcnt(0)" ::: "memory")
#define LDSFENCE() asm volatile("s_waitcnt lgkmcnt(0)" ::: "memory")

__device__ __forceinline__ int expof(float x) {
    return (int)((__float_as_uint(x) >> 23) & 0xff) - 127;
}

__global__ __launch_bounds__(256) void kFB(const float* __restrict__ T,
                                           const float* __restrict__ Pi,
                                           const int* __restrict__ obs,
                                           float* __restrict__ out,
                                           float* __restrict__ ws)
{
    __shared__ float sM[CHK * 64];
    __shared__ float sDuty[GSZ * 64];
    __shared__ float sG2[NGRP * 64];
    __shared__ float sGP[GSZ * 64];
    __shared__ float sA[(CHK + 1) * 8];
    __shared__ float sB[(CHK + 1) * 8];
    __shared__ float sGv[CHK * 8];
    __shared__ int   sObs[CHK + 1];
    unsigned* flg = reinterpret_cast<unsigned*>(ws);
    const int tid = threadIdx.x;
    const int blk = blockIdx.x;

    if (blk >= NCH) {
        // ============= FILL block: pure streaming zeros (no flags) =========
        const int c = blk - NCH;
        const int r0 = c * CHK;
        if (tid < CHK + 1) {
            int t = r0 - 1 + tid;
            sObs[tid] = (t >= 0) ? obs[t] : 0;   // sObs[0]=obs[r0-1]
        }
        __syncthreads();
        float4* o4 = reinterpret_cast<float4*>(out);
        const float4 z = make_float4(0.f, 0.f, 0.f, 0.f);
        // main: channel-phase-rotated sweep; per row rr, skip window float4s
#pragma unroll 2
        for (int it = 0; it < 128; ++it) {
            int itr = (it + c) & 127;                // 4KiB-granular rotation
            int q = itr * 256 + tid;                 // [0, 32768)
            int rr = q >> 10, pos = q & 1023;
            int w2 = sObs[1 + rr] * 2;
            if (pos != 0 && (unsigned)(pos - w2) > 2u)
                o4[r0 * 1024 + q] = z;
        }
        // specials: per row rr = tid>>3, role = tid&7
        {
            const int rr = tid >> 3, role = tid & 7;
            const int r = r0 + rr;
            const int ob = sObs[1 + rr];
            const int obPrev = sObs[rr];              // valid when r>0
            const int m = r * 1024 + ob * 2;          // first skipped float4
            const int ks = r * 1024;                  // straddler float4
            const bool fullStraddle = (r != 0) && (obPrev != 511) && (ob != 0);
            if (role == 0) {
                if (fullStraddle) o4[ks] = z;
                else if (r != 0 && obPrev != 511) out[(size_t)4 * ks] = 0.f;   // prev row col 4095
            } else if (role <= 3) {
                if (!fullStraddle && ob != 0) out[(size_t)4 * ks + role] = 0.f; // cols 0..2
            } else if (role <= 6) {
                if (ob <= 510) out[(size_t)4 * m + 9 + (role - 4)] = 0.f;       // cols w+8..w+10
            } else {
                if (ob >= 1) out[(size_t)4 * m] = 0.f;                          // col 8ob-1
            }
            if (tid == 255 && c == NCH - 1 && sObs[CHK] != 511)
                out[(size_t)LSEQ * NSTATES] = 0.f;    // row 8191 col 4095
        }
        return;
    }

    // ==================== SCAN block (wave 0 only) =========================
    if (tid >= 64) return;
    const int b = blk;
    const int g = b >> 4, rIn = b & 15;
    const int t0 = b * CHK;
    const int n = min(CHK, NSTEPS - t0);  // 32; block 255: 31
    float ll0 = 0.f;
    int kTot = 0;
    const int i = tid >> 3, j = tid & 7;

    // ---- gather own chunk's 8x8 T-blocks into LDS -------------------------
    for (int u = tid; u < n * 8; u += 64) {
        int dt = u >> 3, ri = u & 7;
        int t = t0 + dt;
        int row = obs[t] * NBLK + ri;
        int col = obs[t + 1] * NBLK;
        const float4* src = reinterpret_cast<const float4*>(T + (size_t)row * NSTATES + col);
        float4 v0 = src[0], v1 = src[1];
        float vv[8] = {v0.x, v0.y, v0.z, v0.w, v1.x, v1.y, v1.z, v1.w};
        float* base = &sM[dt * 64 + ri];               // [dt*64 + col*8 + row]
#pragma unroll
        for (int jj = 0; jj < 8; ++jj) base[jj * 8] = vv[jj];
    }
    if (tid < CHK) sObs[tid] = obs[t0 + tid];
    LDSFENCE();

    // ---- chunk product (exponent-tracked): lane (i,j) holds P[i][j] ----
    {
        float p = sM[j * 8 + i];
        float m[8], mn[8];
#pragma unroll
        for (int k = 0; k < 8; ++k) m[k] = sM[64 + j * 8 + k];
        for (int dt = 1; dt < n; ++dt) {
            int dtn = min(dt + 1, n - 1);
#pragma unroll
            for (int k = 0; k < 8; ++k) mn[k] = sM[dtn * 64 + j * 8 + k];
            float pn = 0.f;
#pragma unroll
            for (int k = 0; k < 8; ++k) pn = fmaf(__shfl(p, i * 8 + k, 64), m[k], pn);
            if ((dt & 3) == 0) {
                int ke = expof(__shfl(pn, 0, 64));
                pn = ldexpf(pn, -ke);
                kTot += ke;
            }
            p = pn;
#pragma unroll
            for (int k = 0; k < 8; ++k) m[k] = mn[k];
        }
        {
            int ke = expof(__shfl(p, 0, 64));
            p = ldexpf(p, -ke);
            kTot += ke;
        }
        astore(&ws[OFF_P + b * 64 + j * 8 + i], p);
    }
    VMFENCE();
    if (tid == 0) astoreu(&flg[FLG_F1 + b], MAGIC);

    // ---- group duty (blocks 0..15): product of group's 16 P's ----
    if (b < NGRP) {
        for (;;) {
            bool ok = true;
            if (tid < GSZ)
                ok = aloadu(&flg[FLG_F1 + GSZ * b + tid]) == MAGIC;
            if (__all(ok)) break;
            __builtin_amdgcn_s_sleep(1);
        }
        {   // pipelined register staging: 16 loads in flight
            float rb[16];
#pragma unroll
            for (int k = 0; k < 16; ++k)
                rb[k] = aload(&ws[OFF_P + (size_t)b * GSZ * 64 + k * 64 + tid]);
#pragma unroll
            for (int k = 0; k < 16; ++k) sDuty[k * 64 + tid] = rb[k];
        }
        LDSFENCE();
        float p = sDuty[j * 8 + i];
        float m[8], mn[8];
#pragma unroll
        for (int k = 0; k < 8; ++k) m[k] = sDuty[64 + j * 8 + k];
        for (int r = 1; r < GSZ; ++r) {
            int rn = min(r + 1, GSZ - 1);
#pragma unroll
            for (int k = 0; k < 8; ++k) mn[k] = sDuty[rn * 64 + j * 8 + k];
            float pn = 0.f;
#pragma unroll
            for (int k = 0; k < 8; ++k) pn = fmaf(__shfl(p, i * 8 + k, 64), m[k], pn);
            if ((r & 1) == 0 || r == GSZ - 1) {
                int ke = expof(__shfl(pn, 0, 64));
                pn = ldexpf(pn, -ke);
            }
            p = pn;
#pragma unroll
            for (int k = 0; k < 8; ++k) m[k] = mn[k];
        }
        astore(&ws[OFF_G2 + b * 64 + j * 8 + i], p);
        VMFENCE();
        if (tid == 0) astoreu(&flg[FLG_F2 + b], MAGIC);
    }

    // ---- wait for all 16 F2 (transitively covers all F1 payloads) ----
    for (;;) {
        bool ok = true;
        if (tid < NGRP)
            ok = aloadu(&flg[FLG_F2 + tid]) == MAGIC;
        if (__all(ok)) break;
        __builtin_amdgcn_s_sleep(1);
    }
    {   // pipelined staging of sG2 + own group's P (32 loads in flight)
        float ra[16], rb[16];
#pragma unroll
        for (int k = 0; k < 16; ++k) ra[k] = aload(&ws[OFF_G2 + k * 64 + tid]);
#pragma unroll
        for (int k = 0; k < 16; ++k)
            rb[k] = aload(&ws[OFF_P + (size_t)g * GSZ * 64 + k * 64 + tid]);
#pragma unroll
        for (int k = 0; k < 16; ++k) sG2[k * 64 + tid] = ra[k];
#pragma unroll
        for (int k = 0; k < 16; ++k) sGP[k * 64 + tid] = rb[k];
    }
    LDSFENCE();

    if (tid < 16) {
        const int grp = tid >> 3, l8 = tid & 7;
        const int st = grp ? 8 : 1;
        const int boff = grp ? l8 : l8 * 8;
        // ---- redundant global dual scan over 16 group products ----
        float v[8], vb[8];
        {
            float a = Pi[obs[0] * NBLK + l8];
            float s0 = a;
            s0 += __shfl_xor(s0, 1); s0 += __shfl_xor(s0, 2); s0 += __shfl_xor(s0, 4);
            float rs0 = 1.0f / s0;
#pragma unroll
            for (int q = 0; q < 8; ++q) v[q] = grp ? 0.125f : __shfl(a, q, 8) * rs0;
            ll0 = __logf(s0);
        }
        const int cap = grp ? (NGRP - 1 - g) : g;
        if (cap == 0) {
#pragma unroll
            for (int q = 0; q < 8; ++q) vb[q] = v[q];
        }
        for (int r = 0; r < NGRP - 1; ++r) {
            int gi = grp ? (NGRP - 1 - r) : r;
            const float* mb = &sG2[gi * 64 + boff];
            float m[8];
#pragma unroll
            for (int q = 0; q < 8; ++q) m[q] = mb[q * st];
            float u = 0.f;
#pragma unroll
            for (int q = 0; q < 8; ++q) u = fmaf(v[q], m[q], u);
            float s = 0.f;
#pragma unroll
            for (int q = 0; q < 8; ++q) { float x = __shfl(u, q, 8); v[q] = x; s += x; }
            float rs = 1.0f / s;
#pragma unroll
            for (int q = 0; q < 8; ++q) v[q] *= rs;
            if (r + 1 == cap) {
#pragma unroll
                for (int q = 0; q < 8; ++q) vb[q] = v[q];
            }
        }
        // ---- predicated advance to own chunk boundary (<=15 steps) ----
#pragma unroll
        for (int q = 0; q < 8; ++q) v[q] = vb[q];
        const int cnt = grp ? (GSZ - 1 - rIn) : rIn;
        for (int q = 0; q < GSZ - 1; ++q) {
            bool act = q < cnt;
            int qc = act ? q : 0;
            int lc = grp ? (GSZ - 1 - qc) : qc;
            const float* mb = &sGP[lc * 64 + boff];
            float m[8];
#pragma unroll
            for (int k = 0; k < 8; ++k) m[k] = mb[k * st];
            float u = 0.f;
#pragma unroll
            for (int k = 0; k < 8; ++k) u = fmaf(v[k], m[k], u);
            float s = 0.f;
            float vn[8];
#pragma unroll
            for (int k = 0; k < 8; ++k) { float x = __shfl(u, k, 8); vn[k] = x; s += x; }
            float rs = 1.0f / s;
#pragma unroll
            for (int k = 0; k < 8; ++k) v[k] = act ? vn[k] * rs : v[k];
        }
        // ---- per-chunk log-lik from chunk product (replaces 32 logf) ----
        if (grp == 0) {
            float u = 0.f;
#pragma unroll
            for (int q2 = 0; q2 < 8; ++q2)
                u = fmaf(v[q2], sGP[rIn * 64 + l8 * 8 + q2], u);
            float ssum = u;
            ssum += __shfl_xor(ssum, 1); ssum += __shfl_xor(ssum, 2); ssum += __shfl_xor(ssum, 4);
            if (l8 == 0)
                astore(&ws[OFF_LLP + b], __logf(ssum) + (float)kTot * 0.69314718055994531f);
        }
        // ---- within-chunk dual rescan from sM (no logf) ----
        float* hist = grp ? sB : sA;
        hist[(grp ? n : 0) * 8 + l8] = v[l8];
        int mt0 = grp ? (n - 1) : 0;
        float m[8], mn[8];
#pragma unroll
        for (int q = 0; q < 8; ++q) m[q] = sM[mt0 * 64 + boff + q * st];
        for (int rr = 0; rr < n; ++rr) {
            int rn2 = min(rr + 1, n - 1);
            int mtn = grp ? (n - 1 - rn2) : rn2;
#pragma unroll
            for (int q = 0; q < 8; ++q) mn[q] = sM[mtn * 64 + boff + q * st];
            float u = 0.f;
#pragma unroll
            for (int q = 0; q < 8; ++q) u = fmaf(v[q], m[q], u);
            float s = 0.f;
#pragma unroll
            for (int q = 0; q < 8; ++q) { float x = __shfl(u, q, 8); v[q] = x; s += x; }
            float rs = 1.0f / s;
#pragma unroll
            for (int q = 0; q < 8; ++q) v[q] *= rs;
            hist[(grp ? (n - 1 - rr) : (rr + 1)) * 8 + l8] = v[l8];
#pragma unroll
            for (int q = 0; q < 8; ++q) m[q] = mn[q];
        }
    }
    LDSFENCE();   // sA/sB visible across wave 0

    // ---- normalized gamma -> sGv ------------------------------------------
    {
        const int r0l = tid >> 3, ii = tid & 7;
#pragma unroll
        for (int k = 0; k < 4; ++k) {
            int rr = r0l + k * 8;
            float gp = sA[rr * 8 + ii] * sB[rr * 8 + ii];
            float gs = gp;
            gs += __shfl_xor(gs, 1); gs += __shfl_xor(gs, 2); gs += __shfl_xor(gs, 4);
            sGv[rr * 8 + ii] = gp / gs;
        }
    }
    LDSFENCE();
    VMFENCE();
    if (tid == 0) astoreu(&flg[FLG_F3 + b], MAGIC);

    // ---- scatter: lane rr<32 writes row t0+rr's window dwords -------------
    if (tid < CHK) {
        const int r = t0 + tid;
        const int ob = sObs[tid];
        const size_t W = (size_t)r * NSTATES + ob * NBLK;   // gamma flat index
        const float* gv = &sGv[tid * 8];
        out[W + 1] = gv[0];
        out[W + 2] = gv[1];
        out[W + 3] = gv[2];
        reinterpret_cast<float4*>(out)[W / 4 + 1] = make_float4(gv[3], gv[4], gv[5], gv[6]);
        out[W + 8] = gv[7];
    }

    // ---- block 0: deterministic log-lik reduction -> out[0] ---------------
    if (b == 0) {
        for (;;) {
            bool ok = true;
#pragma unroll
            for (int q = 0; q < 4; ++q)
                ok = ok && (aloadu(&flg[FLG_F3 + tid * 4 + q]) == MAGIC);
            if (__all(ok)) break;
            __builtin_amdgcn_s_sleep(1);
        }
        float part = 0.f;
#pragma unroll
        for (int q = 0; q < 4; ++q) part += aload(&ws[OFF_LLP + tid * 4 + q]);
        part += __shfl_xor(part, 32); part += __shfl_xor(part, 16);
        part += __shfl_xor(part, 8);  part += __shfl_xor(part, 4);
        part += __shfl_xor(part, 2);  part += __shfl_xor(part, 1);
        if (tid == 0) out[0] = part + ll0;
    }
}

extern "C" void kernel_launch(void* const* d_in, const int* in_sizes, int n_in,
                              void* d_out, int out_size, void* d_ws, size_t ws_size,
                              hipStream_t stream)
{
    const float* T   = (const float*)d_in[0];
    const float* Pi  = (const float*)d_in[1];
    const int*   obs = (const int*)d_in[2];
    float* out = (float*)d_out;
    float* ws  = (float*)d_ws;

    kFB<<<NCH * 2, 256, 0, stream>>>(T, Pi, obs, out, ws);
}

// Round 16
// 40.852 us; speedup vs baseline: 1.1399x; 1.0081x over previous
//
#include <hip/hip_runtime.h>

// CHMM forward-backward, clone-structured deterministic emission (n_clones=8).
// Single regular-launch kernel, 256 scan + 256 fill blocks x 256 threads.
// Output dwords PARTITIONED by ownership derived from obs (every byte exactly
// one writer -> replay-safe, no fill<->scan ordering).
// R16 theme: cut the SCAN-CHAIN latency (model: scan ~30us is the critical
// path; fill ~20-25us hides under it): (1) fully-unrolled T-gather (8
// independent loads/lane), (2) mn-prefetch in the 15-step global scan and
// advance loops, (3) s_setprio(1) around the scan chain (role-diverse vs
// co-resident fill waves). Fill path identical to R15.

#define NSTATES 4096
#define NBLK    8
#define LSEQ    8192
#define NSTEPS  8191
#define CHK     32
#define NCH     256
#define NGRP    16
#define GSZ     16

// ws float offsets
#define OFF_P   0u       // [NCH*64]  chunk products, col-major [c*64 + col*8 + row]
#define OFF_G2  16384u   // [NGRP*64] group products, col-major
#define OFF_LLP 17408u   // [NCH]     per-chunk log-lik partials
// ws uint offsets (flags)
#define FLG_F1  17664u   // [NCH]
#define FLG_F2  17920u   // [NGRP]
#define FLG_F3  17936u   // [NCH]
#define MAGIC   0x5A17C0DEu

__device__ __forceinline__ float aload(float* p) {
    return __hip_atomic_load(p, __ATOMIC_RELAXED, __HIP_MEMORY_SCOPE_AGENT);
}
__device__ __forceinline__ void astore(float* p, float v) {
    __hip_atomic_store(p, v, __ATOMIC_RELAXED, __HIP_MEMORY_SCOPE_AGENT);
}
__device__ __forceinline__ unsigned aloadu(unsigned* p) {
    return __hip_atomic_load(p, __ATOMIC_RELAXED, __HIP_MEMORY_SCOPE_AGENT);
}
__device__ __forceinline__ void astoreu(unsigned* p, unsigned v) {
    __hip_atomic_store(p, v, __ATOMIC_RELAXED, __HIP_MEMORY_SCOPE_AGENT);
}
#define VMFENCE()  asm volatile("s_waitcnt vmcnt(0)" ::: "memory")
#define LDSFENCE() asm volatile("s_waitcnt lgkmcnt(0)" ::: "memory")

__device__ __forceinline__ int expof(float x) {
    return (int)((__float_as_uint(x) >> 23) & 0xff) - 127;
}

__global__ __launch_bounds__(256) void kFB(const float* __restrict__ T,
                                           const float* __restrict__ Pi,
                                           const int* __restrict__ obs,
                                           float* __restrict__ out,
                                           float* __restrict__ ws)
{
    __shared__ float sM[CHK * 64];
    __shared__ float sDuty[GSZ * 64];
    __shared__ float sG2[NGRP * 64];
    __shared__ float sGP[GSZ * 64];
    __shared__ float sA[(CHK + 1) * 8];
    __shared__ float sB[(CHK + 1) * 8];
    __shared__ float sGv[CHK * 8];
    __shared__ int   sObs[CHK + 1];
    unsigned* flg = reinterpret_cast<unsigned*>(ws);
    const int tid = threadIdx.x;
    const int blk = blockIdx.x;

    if (blk >= NCH) {
        // ============= FILL block: pure streaming zeros (no flags) =========
        const int c = blk - NCH;
        const int r0 = c * CHK;
        if (tid < CHK + 1) {
            int t = r0 - 1 + tid;
            sObs[tid] = (t >= 0) ? obs[t] : 0;   // sObs[0]=obs[r0-1]
        }
        __syncthreads();
        float4* o4 = reinterpret_cast<float4*>(out);
        const float4 z = make_float4(0.f, 0.f, 0.f, 0.f);
        // main: channel-phase-rotated sweep; per row rr, skip window float4s
#pragma unroll 2
        for (int it = 0; it < 128; ++it) {
            int itr = (it + c) & 127;                // 4KiB-granular rotation
            int q = itr * 256 + tid;                 // [0, 32768)
            int rr = q >> 10, pos = q & 1023;
            int w2 = sObs[1 + rr] * 2;
            if (pos != 0 && (unsigned)(pos - w2) > 2u)
                o4[r0 * 1024 + q] = z;
        }
        // specials: per row rr = tid>>3, role = tid&7
        {
            const int rr = tid >> 3, role = tid & 7;
            const int r = r0 + rr;
            const int ob = sObs[1 + rr];
            const int obPrev = sObs[rr];              // valid when r>0
            const int m = r * 1024 + ob * 2;          // first skipped float4
            const int ks = r * 1024;                  // straddler float4
            const bool fullStraddle = (r != 0) && (obPrev != 511) && (ob != 0);
            if (role == 0) {
                if (fullStraddle) o4[ks] = z;
                else if (r != 0 && obPrev != 511) out[(size_t)4 * ks] = 0.f;   // prev row col 4095
            } else if (role <= 3) {
                if (!fullStraddle && ob != 0) out[(size_t)4 * ks + role] = 0.f; // cols 0..2
            } else if (role <= 6) {
                if (ob <= 510) out[(size_t)4 * m + 9 + (role - 4)] = 0.f;       // cols w+8..w+10
            } else {
                if (ob >= 1) out[(size_t)4 * m] = 0.f;                          // col 8ob-1
            }
            if (tid == 255 && c == NCH - 1 && sObs[CHK] != 511)
                out[(size_t)LSEQ * NSTATES] = 0.f;    // row 8191 col 4095
        }
        return;
    }

    // ==================== SCAN block (wave 0 only) =========================
    if (tid >= 64) return;
    __builtin_amdgcn_s_setprio(1);        // critical wave vs co-resident fill
    const int b = blk;
    const int g = b >> 4, rIn = b & 15;
    const int t0 = b * CHK;
    const int n = min(CHK, NSTEPS - t0);  // 32; block 255: 31
    float ll0 = 0.f;
    int kTot = 0;
    const int i = tid >> 3, j = tid & 7;

    // ---- gather own chunk's 8x8 T-blocks into LDS (fully unrolled) --------
#pragma unroll
    for (int w = 0; w < 4; ++w) {
        int u = tid + 64 * w;
        int dt = u >> 3, ri = u & 7;
        if (dt < n) {
            int t = t0 + dt;
            int row = obs[t] * NBLK + ri;
            int col = obs[t + 1] * NBLK;
            const float4* src = reinterpret_cast<const float4*>(T + (size_t)row * NSTATES + col);
            float4 v0 = src[0], v1 = src[1];
            float vv[8] = {v0.x, v0.y, v0.z, v0.w, v1.x, v1.y, v1.z, v1.w};
            float* base = &sM[dt * 64 + ri];           // [dt*64 + col*8 + row]
#pragma unroll
            for (int jj = 0; jj < 8; ++jj) base[jj * 8] = vv[jj];
        }
    }
    if (tid < CHK) sObs[tid] = obs[t0 + tid];
    LDSFENCE();

    // ---- chunk product (exponent-tracked): lane (i,j) holds P[i][j] ----
    {
        float p = sM[j * 8 + i];
        float m[8], mn[8];
#pragma unroll
        for (int k = 0; k < 8; ++k) m[k] = sM[64 + j * 8 + k];
        for (int dt = 1; dt < n; ++dt) {
            int dtn = min(dt + 1, n - 1);
#pragma unroll
            for (int k = 0; k < 8; ++k) mn[k] = sM[dtn * 64 + j * 8 + k];
            float pn = 0.f;
#pragma unroll
            for (int k = 0; k < 8; ++k) pn = fmaf(__shfl(p, i * 8 + k, 64), m[k], pn);
            if ((dt & 3) == 0) {
                int ke = expof(__shfl(pn, 0, 64));
                pn = ldexpf(pn, -ke);
                kTot += ke;
            }
            p = pn;
#pragma unroll
            for (int k = 0; k < 8; ++k) m[k] = mn[k];
        }
        {
            int ke = expof(__shfl(p, 0, 64));
            p = ldexpf(p, -ke);
            kTot += ke;
        }
        astore(&ws[OFF_P + b * 64 + j * 8 + i], p);
    }
    VMFENCE();
    if (tid == 0) astoreu(&flg[FLG_F1 + b], MAGIC);

    // ---- group duty (blocks 0..15): product of group's 16 P's ----
    if (b < NGRP) {
        for (;;) {
            bool ok = true;
            if (tid < GSZ)
                ok = aloadu(&flg[FLG_F1 + GSZ * b + tid]) == MAGIC;
            if (__all(ok)) break;
            __builtin_amdgcn_s_sleep(1);
        }
        {   // pipelined register staging: 16 loads in flight
            float rb[16];
#pragma unroll
            for (int k = 0; k < 16; ++k)
                rb[k] = aload(&ws[OFF_P + (size_t)b * GSZ * 64 + k * 64 + tid]);
#pragma unroll
            for (int k = 0; k < 16; ++k) sDuty[k * 64 + tid] = rb[k];
        }
        LDSFENCE();
        float p = sDuty[j * 8 + i];
        float m[8], mn[8];
#pragma unroll
        for (int k = 0; k < 8; ++k) m[k] = sDuty[64 + j * 8 + k];
        for (int r = 1; r < GSZ; ++r) {
            int rn = min(r + 1, GSZ - 1);
#pragma unroll
            for (int k = 0; k < 8; ++k) mn[k] = sDuty[rn * 64 + j * 8 + k];
            float pn = 0.f;
#pragma unroll
            for (int k = 0; k < 8; ++k) pn = fmaf(__shfl(p, i * 8 + k, 64), m[k], pn);
            if ((r & 1) == 0 || r == GSZ - 1) {
                int ke = expof(__shfl(pn, 0, 64));
                pn = ldexpf(pn, -ke);
            }
            p = pn;
#pragma unroll
            for (int k = 0; k < 8; ++k) m[k] = mn[k];
        }
        astore(&ws[OFF_G2 + b * 64 + j * 8 + i], p);
        VMFENCE();
        if (tid == 0) astoreu(&flg[FLG_F2 + b], MAGIC);
    }

    // ---- wait for all 16 F2 (transitively covers all F1 payloads) ----
    for (;;) {
        bool ok = true;
        if (tid < NGRP)
            ok = aloadu(&flg[FLG_F2 + tid]) == MAGIC;
        if (__all(ok)) break;
        __builtin_amdgcn_s_sleep(1);
    }
    {   // pipelined staging of sG2 + own group's P (32 loads in flight)
        float ra[16], rb[16];
#pragma unroll
        for (int k = 0; k < 16; ++k) ra[k] = aload(&ws[OFF_G2 + k * 64 + tid]);
#pragma unroll
        for (int k = 0; k < 16; ++k)
            rb[k] = aload(&ws[OFF_P + (size_t)g * GSZ * 64 + k * 64 + tid]);
#pragma unroll
        for (int k = 0; k < 16; ++k) sG2[k * 64 + tid] = ra[k];
#pragma unroll
        for (int k = 0; k < 16; ++k) sGP[k * 64 + tid] = rb[k];
    }
    LDSFENCE();

    if (tid < 16) {
        const int grp = tid >> 3, l8 = tid & 7;
        const int st = grp ? 8 : 1;
        const int boff = grp ? l8 : l8 * 8;
        // ---- redundant global dual scan over 16 group products (prefetch) --
        float v[8], vb[8];
        {
            float a = Pi[obs[0] * NBLK + l8];
            float s0 = a;
            s0 += __shfl_xor(s0, 1); s0 += __shfl_xor(s0, 2); s0 += __shfl_xor(s0, 4);
            float rs0 = 1.0f / s0;
#pragma unroll
            for (int q = 0; q < 8; ++q) v[q] = grp ? 0.125f : __shfl(a, q, 8) * rs0;
            ll0 = __logf(s0);
        }
        const int cap = grp ? (NGRP - 1 - g) : g;
        if (cap == 0) {
#pragma unroll
            for (int q = 0; q < 8; ++q) vb[q] = v[q];
        }
        {
            float m[8], mn[8];
            int gi0 = grp ? (NGRP - 1) : 0;
#pragma unroll
            for (int q = 0; q < 8; ++q) m[q] = sG2[gi0 * 64 + boff + q * st];
            for (int r = 0; r < NGRP - 1; ++r) {
                int rp = min(r + 1, NGRP - 2);
                int gin = grp ? (NGRP - 1 - rp) : rp;
#pragma unroll
                for (int q = 0; q < 8; ++q) mn[q] = sG2[gin * 64 + boff + q * st];
                float u = 0.f;
#pragma unroll
                for (int q = 0; q < 8; ++q) u = fmaf(v[q], m[q], u);
                float s = 0.f;
#pragma unroll
                for (int q = 0; q < 8; ++q) { float x = __shfl(u, q, 8); v[q] = x; s += x; }
                float rs = 1.0f / s;
#pragma unroll
                for (int q = 0; q < 8; ++q) v[q] *= rs;
                if (r + 1 == cap) {
#pragma unroll
                    for (int q = 0; q < 8; ++q) vb[q] = v[q];
                }
#pragma unroll
                for (int q = 0; q < 8; ++q) m[q] = mn[q];
            }
        }
        // ---- predicated advance to own chunk boundary (prefetch) ----
#pragma unroll
        for (int q = 0; q < 8; ++q) v[q] = vb[q];
        const int cnt = grp ? (GSZ - 1 - rIn) : rIn;
        {
            float m[8], mn[8];
            int lc0 = grp ? (GSZ - 1) : 0;
#pragma unroll
            for (int k = 0; k < 8; ++k) m[k] = sGP[lc0 * 64 + boff + k * st];
            for (int q = 0; q < GSZ - 1; ++q) {
                bool act = q < cnt;
                int qn = q + 1 < cnt ? q + 1 : 0;
                int lcn = grp ? (GSZ - 1 - qn) : qn;
#pragma unroll
                for (int k = 0; k < 8; ++k) mn[k] = sGP[lcn * 64 + boff + k * st];
                float u = 0.f;
#pragma unroll
                for (int k = 0; k < 8; ++k) u = fmaf(v[k], m[k], u);
                float s = 0.f;
                float vn[8];
#pragma unroll
                for (int k = 0; k < 8; ++k) { float x = __shfl(u, k, 8); vn[k] = x; s += x; }
                float rs = 1.0f / s;
#pragma unroll
                for (int k = 0; k < 8; ++k) v[k] = act ? vn[k] * rs : v[k];
#pragma unroll
                for (int k = 0; k < 8; ++k) m[k] = mn[k];
            }
        }
        // ---- per-chunk log-lik from chunk product (replaces 32 logf) ----
        if (grp == 0) {
            float u = 0.f;
#pragma unroll
            for (int q2 = 0; q2 < 8; ++q2)
                u = fmaf(v[q2], sGP[rIn * 64 + l8 * 8 + q2], u);
            float ssum = u;
            ssum += __shfl_xor(ssum, 1); ssum += __shfl_xor(ssum, 2); ssum += __shfl_xor(ssum, 4);
            if (l8 == 0)
                astore(&ws[OFF_LLP + b], __logf(ssum) + (float)kTot * 0.69314718055994531f);
        }
        // ---- within-chunk dual rescan from sM (prefetched) ----
        float* hist = grp ? sB : sA;
        hist[(grp ? n : 0) * 8 + l8] = v[l8];
        int mt0 = grp ? (n - 1) : 0;
        float m[8], mn[8];
#pragma unroll
        for (int q = 0; q < 8; ++q) m[q] = sM[mt0 * 64 + boff + q * st];
        for (int rr = 0; rr < n; ++rr) {
            int rn2 = min(rr + 1, n - 1);
            int mtn = grp ? (n - 1 - rn2) : rn2;
#pragma unroll
            for (int q = 0; q < 8; ++q) mn[q] = sM[mtn * 64 + boff + q * st];
            float u = 0.f;
#pragma unroll
            for (int q = 0; q < 8; ++q) u = fmaf(v[q], m[q], u);
            float s = 0.f;
#pragma unroll
            for (int q = 0; q < 8; ++q) { float x = __shfl(u, q, 8); v[q] = x; s += x; }
            float rs = 1.0f / s;
#pragma unroll
            for (int q = 0; q < 8; ++q) v[q] *= rs;
            hist[(grp ? (n - 1 - rr) : (rr + 1)) * 8 + l8] = v[l8];
#pragma unroll
            for (int q = 0; q < 8; ++q) m[q] = mn[q];
        }
    }
    LDSFENCE();   // sA/sB visible across wave 0

    // ---- normalized gamma -> sGv ------------------------------------------
    {
        const int r0l = tid >> 3, ii = tid & 7;
#pragma unroll
        for (int k = 0; k < 4; ++k) {
            int rr = r0l + k * 8;
            float gp = sA[rr * 8 + ii] * sB[rr * 8 + ii];
            float gs = gp;
            gs += __shfl_xor(gs, 1); gs += __shfl_xor(gs, 2); gs += __shfl_xor(gs, 4);
            sGv[rr * 8 + ii] = gp / gs;
        }
    }
    LDSFENCE();
    VMFENCE();
    if (tid == 0) astoreu(&flg[FLG_F3 + b], MAGIC);
    __builtin_amdgcn_s_setprio(0);

    // ---- scatter: lane rr<32 writes row t0+rr's window dwords -------------
    if (tid < CHK) {
        const int r = t0 + tid;
        const int ob = sObs[tid];
        const size_t W = (size_t)r * NSTATES + ob * NBLK;   // gamma flat index
        const float* gv = &sGv[tid * 8];
        out[W + 1] = gv[0];
        out[W + 2] = gv[1];
        out[W + 3] = gv[2];
        reinterpret_cast<float4*>(out)[W / 4 + 1] = make_float4(gv[3], gv[4], gv[5], gv[6]);
        out[W + 8] = gv[7];
    }

    // ---- block 0: deterministic log-lik reduction -> out[0] ---------------
    if (b == 0) {
        for (;;) {
            bool ok = true;
#pragma unroll
            for (int q = 0; q < 4; ++q)
                ok = ok && (aloadu(&flg[FLG_F3 + tid * 4 + q]) == MAGIC);
            if (__all(ok)) break;
            __builtin_amdgcn_s_sleep(1);
        }
        float part = 0.f;
#pragma unroll
        for (int q = 0; q < 4; ++q) part += aload(&ws[OFF_LLP + tid * 4 + q]);
        part += __shfl_xor(part, 32); part += __shfl_xor(part, 16);
        part += __shfl_xor(part, 8);  part += __shfl_xor(part, 4);
        part += __shfl_xor(part, 2);  part += __shfl_xor(part, 1);
        if (tid == 0) out[0] = part + ll0;
    }
}

extern "C" void kernel_launch(void* const* d_in, const int* in_sizes, int n_in,
                              void* d_out, int out_size, void* d_ws, size_t ws_size,
                              hipStream_t stream)
{
    const float* T   = (const float*)d_in[0];
    const float* Pi  = (const float*)d_in[1];
    const int*   obs = (const int*)d_in[2];
    float* out = (float*)d_out;
    float* ws  = (float*)d_ws;

    kFB<<<NCH * 2, 256, 0, stream>>>(T, Pi, obs, out, ws);
}